// Round 6
// baseline (345.247 us; speedup 1.0000x reference)
//
#include <hip/hip_runtime.h>

typedef __attribute__((ext_vector_type(4))) float f32x4;
typedef __attribute__((ext_vector_type(16))) float f32x16;
typedef __attribute__((ext_vector_type(8))) _Float16 f16x8;
typedef __attribute__((ext_vector_type(4))) _Float16 f16x4;

__device__ __forceinline__ void gload_lds16(const void* g, void* l) {
  __builtin_amdgcn_global_load_lds((__attribute__((address_space(1))) void*)(g),
                                   (__attribute__((address_space(3))) void*)(l), 16, 0, 0);
}

#define BAR() asm volatile("s_barrier" ::: "memory")
#define WAITV6() asm volatile("s_waitcnt vmcnt(6)" ::: "memory")
#define WAITV4() asm volatile("s_waitcnt vmcnt(4)" ::: "memory")
#define WAITV0() asm volatile("s_waitcnt vmcnt(0)" ::: "memory")

// ---- fused prep: cast H fp32->fp16 (blocks 0..8191) + weight transpose-cast ----
__global__ __launch_bounds__(256) void prep(const float* __restrict__ Hs,
                                            const float* __restrict__ W0, const float* __restrict__ W1,
                                            const float* __restrict__ W2, const float* __restrict__ W3,
                                            _Float16* __restrict__ Hb, _Float16* __restrict__ Wt) {
  __shared__ _Float16 tile[64][65];
  const int bid = blockIdx.x, tid = threadIdx.x;
  if (bid < 8192) {
    int i = (bid * 256 + tid) * 4;
    float4 v = *(const float4*)(Hs + i);
    f16x4 o = { (_Float16)v.x, (_Float16)v.y, (_Float16)v.z, (_Float16)v.w };
    *(f16x4*)(Hb + i) = o;
    return;
  }
  const int t = bid - 8192;
  const int z = t >> 10, k0 = ((t >> 5) & 31) * 64, n0 = (t & 31) * 64;
  const float* W = z == 0 ? W0 : z == 1 ? W1 : z == 2 ? W2 : W3;
  _Float16* Wo_ = Wt + (size_t)z * (2048u * 2048u);
  #pragma unroll
  for (int p = 0; p < 4; ++p) {
    int o = p * 256 + tid, r = o >> 4, c = o & 15;
    float4 v = *(const float4*)(W + (size_t)(k0 + r) * 2048 + n0 + c * 4);
    tile[r][c * 4 + 0] = (_Float16)v.x;
    tile[r][c * 4 + 1] = (_Float16)v.y;
    tile[r][c * 4 + 2] = (_Float16)v.z;
    tile[r][c * 4 + 3] = (_Float16)v.w;
  }
  __syncthreads();
  #pragma unroll
  for (int p = 0; p < 2; ++p) {
    int o = p * 256 + tid, nl = o >> 3, c = o & 7;
    f16x8 u;
    #pragma unroll
    for (int i = 0; i < 8; ++i) u[i] = tile[c * 8 + i][nl];
    *(f16x8*)(Wo_ + (size_t)(n0 + nl) * 2048 + k0 + c * 8) = u;
  }
}

// ---- 256x256 pipelined GEMM, overlap schedule (R2's proven engine).
// 512 thr = 8 waves (2M x 4N), wave tile 128x64, BK=64, K=2048 (32 tiles).
// LDS 128 KB double buffer. 3 barriers / K-tile; counted vmcnt(6).
// Hazard ledger: see R2 (verified over 3 passing rounds).
__device__ __forceinline__ void gemm256(const _Float16* __restrict__ A,
                                        const _Float16* __restrict__ Bt,
                                        _Float16* __restrict__ C, int ldc,
                                        int m0, int n0, _Float16* S) {
  _Float16* const As0 = S;
  _Float16* const As1 = S + 16384;
  _Float16* const Bs0 = S + 32768;
  _Float16* const Bs1 = S + 49152;
  const int tid = (int)threadIdx.x;
  const int lane = tid & 63, w = tid >> 6, l32 = lane & 31, half = lane >> 5;
  const int wm = (w & 1) * 128, wn = (w >> 1) * 64;

  f32x16 acc[4][2];
  #pragma unroll
  for (int s = 0; s < 4; ++s)
    #pragma unroll
    for (int t = 0; t < 2; ++t) acc[s][t] = 0;

  f16x8 af[2][4];
  f16x8 bf[2][4];

  auto stageA = [&](_Float16* dst, int ar, int kt) {
    const int r = tid >> 3, c = tid & 7;
    gload_lds16(A + (size_t)(m0 + ar + r) * 2048 + kt * 64 + ((c ^ (r & 7)) << 3),
                (char*)dst + ar * 128 + tid * 16);
  };
  auto stageB = [&](_Float16* dst, int br, int kt) {
    const int r = tid >> 3, c = tid & 7;
    gload_lds16(Bt + (size_t)(n0 + br + r) * 2048 + kt * 64 + ((c ^ (r & 7)) << 3),
                (char*)dst + br * 128 + tid * 16);
  };
  auto ldA = [&](const _Float16* as, int p) {
    #pragma unroll
    for (int s2 = 0; s2 < 2; ++s2)
      #pragma unroll
      for (int kk = 0; kk < 4; ++kk)
        af[s2][kk] = *(const f16x8*)(as + (wm + p * 64 + s2 * 32 + l32) * 64 +
                                     (((2 * kk + half) ^ (l32 & 7)) << 3));
  };
  auto ldB = [&](const _Float16* bs, int q) {
    #pragma unroll
    for (int kk = 0; kk < 4; ++kk)
      bf[q][kk] = *(const f16x8*)(bs + (wn + q * 32 + l32) * 64 +
                                  (((2 * kk + half) ^ (l32 & 7)) << 3));
  };
  auto mm8 = [&](int sp, int q) {
    __builtin_amdgcn_s_setprio(1);
    #pragma unroll
    for (int kk = 0; kk < 4; ++kk)
      #pragma unroll
      for (int s2 = 0; s2 < 2; ++s2)
        acc[sp * 2 + s2][q] = __builtin_amdgcn_mfma_f32_32x32x16_f16(
            bf[q][kk], af[s2][kk], acc[sp * 2 + s2][q], 0, 0, 0);
    __builtin_amdgcn_s_setprio(0);
  };

  stageA(As0, 0, 0); stageA(As0, 64, 0); stageA(As0, 128, 0); stageA(As0, 192, 0);
  stageB(Bs0, 0, 0); stageB(Bs0, 64, 0); stageB(Bs0, 128, 0); stageB(Bs0, 192, 0);
  stageA(As1, 0, 1); stageA(As1, 128, 1);
  stageB(Bs1, 0, 1); stageB(Bs1, 64, 1); stageB(Bs1, 128, 1); stageB(Bs1, 192, 1);
  WAITV6();
  BAR();

  auto tile = [&](int kt, _Float16* Ac, _Float16* Bc, _Float16* An) {
    const bool g1 = (kt + 1) < 32, g2 = (kt + 2) < 32;
    ldA(Ac, 0);
    ldB(Bc, 0); ldB(Bc, 1);
    if (g1) { stageA(An, 64, kt + 1); stageA(An, 192, kt + 1); }
    mm8(0, 0);
    BAR();                      // B1
    if (g2) { stageA(Ac, 0, kt + 2); stageA(Ac, 128, kt + 2); }
    mm8(0, 1);
    BAR();                      // B2
    ldA(Ac, 1);
    if (g2) { stageB(Bc, 0, kt + 2); stageB(Bc, 64, kt + 2);
              stageB(Bc, 128, kt + 2); stageB(Bc, 192, kt + 2); }
    mm8(1, 1);
    mm8(1, 0);
    if (g2) { WAITV6(); } else { WAITV0(); }
    BAR();                      // B3
  };

  #pragma unroll 1
  for (int kt = 0; kt < 32; kt += 2) {
    tile(kt, As0, Bs0, As1);
    tile(kt + 1, As1, Bs1, As0);
  }

  #pragma unroll
  for (int s = 0; s < 4; ++s) {
    const size_t row = (size_t)(wm + s * 32 + l32);
    #pragma unroll
    for (int t = 0; t < 2; ++t)
      #pragma unroll
      for (int g = 0; g < 4; ++g) {
        const int col = wn + t * 32 + g * 8 + 4 * half;
        f16x4 o = { (_Float16)acc[s][t][4 * g + 0], (_Float16)acc[s][t][4 * g + 1],
                    (_Float16)acc[s][t][4 * g + 2], (_Float16)acc[s][t][4 * g + 3] };
        *(f16x4*)(C + row * ldc + col) = o;
      }
  }
}

// ---- 128x256 pipelined GEMM engine (R2 component). 8 waves (2M x 4N), wave
// tile 64x64, acc 2x2, LDS 96 KB, 2 barriers/K-tile, vmcnt(6). ----
template <typename OutT>
__device__ __forceinline__ void gemm128(const _Float16* __restrict__ A,
                                        const _Float16* __restrict__ Bt,
                                        OutT* __restrict__ C, int ldc,
                                        int m0, int n0, _Float16* S) {
  _Float16* const As0 = S;             // 128 x 64
  _Float16* const As1 = S + 8192;
  _Float16* const Bs0 = S + 16384;     // 256 x 64
  _Float16* const Bs1 = S + 32768;
  const int tid = (int)threadIdx.x;
  const int lane = tid & 63, w = tid >> 6, l32 = lane & 31, half = lane >> 5;
  const int wm = (w & 1) * 64, wn = (w >> 1) * 64;

  f32x16 acc[2][2];
  #pragma unroll
  for (int s = 0; s < 2; ++s)
    #pragma unroll
    for (int t = 0; t < 2; ++t) acc[s][t] = 0;

  f16x8 af[2][4], bf[2][4];

  auto stA = [&](_Float16* dst, int ar, int kt) {
    const int r = tid >> 3, c = tid & 7;
    gload_lds16(A + (size_t)(m0 + ar + r) * 2048 + kt * 64 + ((c ^ (r & 7)) << 3),
                (char*)dst + ar * 128 + tid * 16);
  };
  auto stB = [&](_Float16* dst, int br, int kt) {
    const int r = tid >> 3, c = tid & 7;
    gload_lds16(Bt + (size_t)(n0 + br + r) * 2048 + kt * 64 + ((c ^ (r & 7)) << 3),
                (char*)dst + br * 128 + tid * 16);
  };
  auto ldAq = [&](const _Float16* as) {
    #pragma unroll
    for (int s2 = 0; s2 < 2; ++s2)
      #pragma unroll
      for (int kk = 0; kk < 4; ++kk)
        af[s2][kk] = *(const f16x8*)(as + (wm + s2 * 32 + l32) * 64 +
                                     (((2 * kk + half) ^ (l32 & 7)) << 3));
  };
  auto ldBq = [&](const _Float16* bs, int q) {
    #pragma unroll
    for (int kk = 0; kk < 4; ++kk)
      bf[q][kk] = *(const f16x8*)(bs + (wn + q * 32 + l32) * 64 +
                                  (((2 * kk + half) ^ (l32 & 7)) << 3));
  };
  auto mmq = [&](int q) {
    __builtin_amdgcn_s_setprio(1);
    #pragma unroll
    for (int kk = 0; kk < 4; ++kk)
      #pragma unroll
      for (int s2 = 0; s2 < 2; ++s2)
        acc[s2][q] = __builtin_amdgcn_mfma_f32_32x32x16_f16(
            bf[q][kk], af[s2][kk], acc[s2][q], 0, 0, 0);
    __builtin_amdgcn_s_setprio(0);
  };

  stA(As0, 0, 0); stA(As0, 64, 0);
  stB(Bs0, 0, 0); stB(Bs0, 64, 0); stB(Bs0, 128, 0); stB(Bs0, 192, 0);
  stA(As1, 0, 1); stA(As1, 64, 1);
  stB(Bs1, 0, 1); stB(Bs1, 64, 1); stB(Bs1, 128, 1); stB(Bs1, 192, 1);
  WAITV6();
  BAR();

  auto tile = [&](int kt, _Float16* Ac, _Float16* Bc) {
    const bool g2 = (kt + 2) < 32;
    ldAq(Ac); ldBq(Bc, 0); ldBq(Bc, 1);
    mmq(0);
    mmq(1);
    BAR();
    if (g2) {
      stA(Ac, 0, kt + 2); stA(Ac, 64, kt + 2);
      stB(Bc, 0, kt + 2); stB(Bc, 64, kt + 2); stB(Bc, 128, kt + 2); stB(Bc, 192, kt + 2);
      WAITV6();
    } else {
      WAITV0();
    }
    BAR();
  };

  #pragma unroll 1
  for (int kt = 0; kt < 32; kt += 2) {
    tile(kt, As0, Bs0);
    tile(kt + 1, As1, Bs1);
  }

  #pragma unroll
  for (int s = 0; s < 2; ++s) {
    const size_t row = (size_t)(wm + s * 32 + l32);
    #pragma unroll
    for (int t = 0; t < 2; ++t)
      #pragma unroll
      for (int g = 0; g < 4; ++g) {
        const int col = wn + t * 32 + g * 8 + 4 * half;
        if constexpr (sizeof(OutT) == 2) {
          f16x4 o = { (_Float16)acc[s][t][4 * g + 0], (_Float16)acc[s][t][4 * g + 1],
                      (_Float16)acc[s][t][4 * g + 2], (_Float16)acc[s][t][4 * g + 3] };
          *(f16x4*)((_Float16*)C + row * ldc + col) = o;
        } else {
          f32x4 o = { acc[s][t][4 * g + 0], acc[s][t][4 * g + 1],
                      acc[s][t][4 * g + 2], acc[s][t][4 * g + 3] };
          *(f32x4*)((float*)C + row * ldc + col) = o;
        }
      }
  }
}

// ---- Q|K GEMM: 256 WGs x 512 thr, 1 WG/CU. C[4096][4096] = Hb . [Wq;Wk]^T ----
__global__ __launch_bounds__(512, 2) void qk(const _Float16* __restrict__ Hb,
                                             const _Float16* __restrict__ Wt,
                                             _Float16* __restrict__ Qb,
                                             _Float16* __restrict__ Kb) {
  __shared__ _Float16 S[65536];  // 128 KB
  const int id = blockIdx.x;
  const int m0 = (id >> 4) * 256, n0 = (id & 15) * 256;
  _Float16* Cq = (n0 < 2048 ? Qb + n0 : Kb + (n0 - 2048)) + (size_t)m0 * 2048;
  gemm256(Hb, Wt, Cq, 2048, m0, n0, S);
}

// ---- V^T GEMM: 256 WGs x 512 thr, 1 WG/CU. C[2048][4096] = WvT . Hb^T ----
__global__ __launch_bounds__(512, 2) void vt(const _Float16* __restrict__ Hb,
                                             const _Float16* __restrict__ WvT,
                                             _Float16* __restrict__ Vtb) {
  __shared__ _Float16 S[49152];  // 96 KB
  const int id = blockIdx.x;
  const int m0 = (id >> 4) * 128, n0 = (id & 15) * 256;
  gemm128<_Float16>(WvT, Hb, Vtb + (size_t)m0 * 4096 + n0, 4096, m0, n0, S);
}

// ---- Wo GEMM: pipelined 128x256 engine, 256 WGs (32m x 8n), 1/CU, f32 out ----
__global__ __launch_bounds__(512, 2) void gemm_wo(const _Float16* __restrict__ A,
                                                  const _Float16* __restrict__ Bt,
                                                  float* __restrict__ C) {
  __shared__ _Float16 S[49152];  // 96 KB
  const int t = blockIdx.x;
  const int m0 = (t >> 3) * 128, n0 = (t & 7) * 256;
  gemm128<float>(A, Bt, C + (size_t)m0 * 2048 + n0, 2048, m0, n0, S);
}

// ---- block-sparse attention: split K/V drain (R5 version) ----
__global__ __launch_bounds__(256) void attn(const _Float16* __restrict__ Qg,
                                            const _Float16* __restrict__ Kg,
                                            const _Float16* __restrict__ Vtg,
                                            _Float16* __restrict__ Og) {
  const int t = blockIdx.x, h = blockIdx.y, b = blockIdx.z;
  __shared__ _Float16 Qs[128 * 128];  // 32 KB
  __shared__ _Float16 Ks[64 * 128];   // 16 KB
  __shared__ _Float16 Vs[128 * 64];   // 16 KB
  const int tid = threadIdx.x;
  const int lane = tid & 63, w = tid >> 6, l16 = lane & 15, quad = lane >> 4;
  const int qbw = 2 * t + (w >> 1);
  const char* QsB = (const char*)Qs;
  const char* KsB = (const char*)Ks;
  const char* VsB = (const char*)Vs;

  #pragma unroll
  for (int p = 0; p < 8; ++p) {
    int o = p * 256 + tid, r = o >> 4, c = o & 15;
    gload_lds16(Qg + (size_t)(b * 2048 + t * 128 + r) * 2048 + h * 128 + ((c ^ (r & 15)) * 8),
                (char*)Qs + o * 16);
  }
  __builtin_amdgcn_s_waitcnt(0);
  __syncthreads();
  f16x8 qf[2][4];
  #pragma unroll
  for (int qc = 0; qc < 2; ++qc)
    #pragma unroll
    for (int ks = 0; ks < 4; ++ks)
      qf[qc][ks] = *(const f16x8*)(QsB + (w * 32 + qc * 16 + l16) * 256 +
                                   (((ks * 4 + quad) ^ l16) * 16));

  const float scale = 0.08838834764831845f;  // 1/sqrt(128)
  float m_[2] = {-1e30f, -1e30f}, l_[2] = {0.f, 0.f};
  f32x4 oacc[8][2];
  #pragma unroll
  for (int dt = 0; dt < 8; ++dt)
    #pragma unroll
    for (int qc = 0; qc < 2; ++qc) oacc[dt][qc] = (f32x4){0.f, 0.f, 0.f, 0.f};

  for (int jj = 0; jj < 6; ++jj) {
    const int j = 2 * t - 2 + jj;
    const int jc = j < 0 ? 0 : (j > 31 ? 31 : j);
    __syncthreads();   // WAR: prev iter's Ks/Vs reads complete
    #pragma unroll
    for (int p = 0; p < 4; ++p) {
      int o = p * 256 + tid, r = o >> 4, c = o & 15;
      gload_lds16(Kg + (size_t)(b * 2048 + jc * 64 + r) * 2048 + h * 128 + ((c ^ (r & 15)) * 8),
                  (char*)Ks + o * 16);
    }
    #pragma unroll
    for (int p = 0; p < 4; ++p) {
      int o = p * 256 + tid, d = o >> 3, c = o & 7;
      gload_lds16(Vtg + (size_t)(h * 128 + d) * 4096 + b * 2048 + jc * 64 + ((c ^ (d & 7)) * 8),
                  (char*)Vs + o * 16);
    }
    WAITV4();   // K's 4 chunks retired; V's 4 still in flight
    BAR();

    const bool valid = (j >= 0) && (j <= 31) && (j >= qbw - 2) && (j <= qbw + 2);
    f32x4 sc[4][2];
    f16x4 pb[4][2];
    if (valid) {
      #pragma unroll
      for (int kt = 0; kt < 4; ++kt)
        #pragma unroll
        for (int qc = 0; qc < 2; ++qc) sc[kt][qc] = (f32x4){0.f, 0.f, 0.f, 0.f};
      #pragma unroll
      for (int kt = 0; kt < 4; ++kt)
        #pragma unroll
        for (int ks = 0; ks < 4; ++ks) {
          f16x8 kf = *(const f16x8*)(KsB + (kt * 16 + l16) * 256 + (((ks * 4 + quad) ^ l16) * 16));
          #pragma unroll
          for (int qc = 0; qc < 2; ++qc)
            sc[kt][qc] = __builtin_amdgcn_mfma_f32_16x16x32_f16(kf, qf[qc][ks], sc[kt][qc], 0, 0, 0);
        }
      #pragma unroll
      for (int qc = 0; qc < 2; ++qc) {
        float mj = -1e30f;
        #pragma unroll
        for (int kt = 0; kt < 4; ++kt)
          #pragma unroll
          for (int r = 0; r < 4; ++r) {
            float v = sc[kt][qc][r] * scale;
            sc[kt][qc][r] = v;
            mj = fmaxf(mj, v);
          }
        mj = fmaxf(mj, __shfl_xor(mj, 16));
        mj = fmaxf(mj, __shfl_xor(mj, 32));
        const float mn = fmaxf(m_[qc], mj);
        const float alpha = __expf(m_[qc] - mn);
        float s_ = 0.f;
        #pragma unroll
        for (int kt = 0; kt < 4; ++kt)
          #pragma unroll
          for (int r = 0; r < 4; ++r) {
            float p = __expf(sc[kt][qc][r] - mn);
            sc[kt][qc][r] = p;
            s_ += p;
          }
        s_ += __shfl_xor(s_, 16);
        s_ += __shfl_xor(s_, 32);
        l_[qc] = l_[qc] * alpha + s_;
        m_[qc] = mn;
        #pragma unroll
        for (int dt = 0; dt < 8; ++dt) oacc[dt][qc] *= alpha;
      }
      #pragma unroll
      for (int kt = 0; kt < 4; ++kt)
        #pragma unroll
        for (int qc = 0; qc < 2; ++qc)
          pb[kt][qc] = (f16x4){ (_Float16)sc[kt][qc][0], (_Float16)sc[kt][qc][1],
                                (_Float16)sc[kt][qc][2], (_Float16)sc[kt][qc][3] };
    }
    WAITV0();   // V landed
    BAR();
    if (valid) {
      #pragma unroll
      for (int kt = 0; kt < 4; ++kt) {
        #pragma unroll
        for (int dt = 0; dt < 8; ++dt) {
          f16x4 vv = *(const f16x4*)(VsB + (dt * 16 + l16) * 128 +
                                     (((2 * kt + (quad >> 1)) ^ (l16 & 7)) * 16) + (quad & 1) * 8);
          #pragma unroll
          for (int qc = 0; qc < 2; ++qc)
            oacc[dt][qc] = __builtin_amdgcn_mfma_f32_16x16x16f16(vv, pb[kt][qc], oacc[dt][qc], 0, 0, 0);
        }
      }
    }
  }

  #pragma unroll
  for (int qc = 0; qc < 2; ++qc) {
    const float pinv = 1.0f / l_[qc];
    const size_t orow = (size_t)(b * 2048 + t * 128 + w * 32 + qc * 16 + l16);
    #pragma unroll
    for (int dt = 0; dt < 8; ++dt) {
      f16x4 ov = { (_Float16)(oacc[dt][qc][0] * pinv), (_Float16)(oacc[dt][qc][1] * pinv),
                   (_Float16)(oacc[dt][qc][2] * pinv), (_Float16)(oacc[dt][qc][3] * pinv) };
      *(f16x4*)(Og + orow * 2048 + h * 128 + dt * 16 + quad * 4) = ov;
    }
  }
}

extern "C" void kernel_launch(void* const* d_in, const int* in_sizes, int n_in,
                              void* d_out, int out_size, void* d_ws, size_t ws_size,
                              hipStream_t stream) {
  const float* Hs = (const float*)d_in[0];
  const float* Wq = (const float*)d_in[1];
  const float* Wk = (const float*)d_in[2];
  const float* Wv = (const float*)d_in[3];
  const float* Wo = (const float*)d_in[4];
  _Float16* Hb  = (_Float16*)d_ws;          // H cast  [4096][2048]
  _Float16* Wt  = Hb  + 8388608;            // Wq/Wk/Wv/Wo^T  4 x [2048][2048]
  _Float16* Qb  = Wt  + 16777216;           // Q  [b*2048+s][h*128+d]
  _Float16* Kb  = Qb  + 8388608;            // K  [b*2048+s][h*128+d]
  _Float16* Vtb = Kb  + 8388608;            // V^T [h*128+d][b*2048+s]
  _Float16* Ob  = Vtb + 8388608;            // attn out [b*2048+s][h*128+d]
  float* out = (float*)d_out;

  prep<<<12288, 256, 0, stream>>>(Hs, Wq, Wk, Wv, Wo, Hb, Wt);
  qk<<<256, 512, 0, stream>>>(Hb, Wt, Qb, Kb);
  vt<<<256, 512, 0, stream>>>(Hb, Wt + (size_t)2 * 4194304, Vtb);
  attn<<<dim3(16, 16, 2), 256, 0, stream>>>(Qb, Kb, Vtb, Ob);
  gemm_wo<<<256, 512, 0, stream>>>(Ob, Wt + (size_t)3 * 4194304, out);
}

// Round 7
// 343.807 us; speedup vs baseline: 1.0042x; 1.0042x over previous
//
#include <hip/hip_runtime.h>

typedef __attribute__((ext_vector_type(4))) float f32x4;
typedef __attribute__((ext_vector_type(16))) float f32x16;
typedef __attribute__((ext_vector_type(8))) _Float16 f16x8;
typedef __attribute__((ext_vector_type(4))) _Float16 f16x4;

__device__ __forceinline__ void gload_lds16(const void* g, void* l) {
  __builtin_amdgcn_global_load_lds((__attribute__((address_space(1))) void*)(g),
                                   (__attribute__((address_space(3))) void*)(l), 16, 0, 0);
}

#define BAR() asm volatile("s_barrier" ::: "memory")
#define WAITV8() asm volatile("s_waitcnt vmcnt(8)" ::: "memory")
#define WAITV6() asm volatile("s_waitcnt vmcnt(6)" ::: "memory")
#define WAITV4() asm volatile("s_waitcnt vmcnt(4)" ::: "memory")
#define WAITV0() asm volatile("s_waitcnt vmcnt(0)" ::: "memory")

// ---- fused prep: cast H fp32->fp16 (blocks 0..8191) + weight transpose-cast ----
__global__ __launch_bounds__(256) void prep(const float* __restrict__ Hs,
                                            const float* __restrict__ W0, const float* __restrict__ W1,
                                            const float* __restrict__ W2, const float* __restrict__ W3,
                                            _Float16* __restrict__ Hb, _Float16* __restrict__ Wt) {
  __shared__ _Float16 tile[64][65];
  const int bid = blockIdx.x, tid = threadIdx.x;
  if (bid < 8192) {
    int i = (bid * 256 + tid) * 4;
    float4 v = *(const float4*)(Hs + i);
    f16x4 o = { (_Float16)v.x, (_Float16)v.y, (_Float16)v.z, (_Float16)v.w };
    *(f16x4*)(Hb + i) = o;
    return;
  }
  const int t = bid - 8192;
  const int z = t >> 10, k0 = ((t >> 5) & 31) * 64, n0 = (t & 31) * 64;
  const float* W = z == 0 ? W0 : z == 1 ? W1 : z == 2 ? W2 : W3;
  _Float16* Wo_ = Wt + (size_t)z * (2048u * 2048u);
  #pragma unroll
  for (int p = 0; p < 4; ++p) {
    int o = p * 256 + tid, r = o >> 4, c = o & 15;
    float4 v = *(const float4*)(W + (size_t)(k0 + r) * 2048 + n0 + c * 4);
    tile[r][c * 4 + 0] = (_Float16)v.x;
    tile[r][c * 4 + 1] = (_Float16)v.y;
    tile[r][c * 4 + 2] = (_Float16)v.z;
    tile[r][c * 4 + 3] = (_Float16)v.w;
  }
  __syncthreads();
  #pragma unroll
  for (int p = 0; p < 2; ++p) {
    int o = p * 256 + tid, nl = o >> 3, c = o & 7;
    f16x8 u;
    #pragma unroll
    for (int i = 0; i < 8; ++i) u[i] = tile[c * 8 + i][nl];
    *(f16x8*)(Wo_ + (size_t)(n0 + nl) * 2048 + k0 + c * 8) = u;
  }
}

// ---- 256x256 pipelined GEMM, 2-barrier schedule (gemm128's proven ledger class).
// 512 thr = 8 waves (2M x 4N), wave tile 128x64, BK=64, K=2048 (32 tiles).
// LDS 128 KB double buffer. Per K-tile:
//   [24 frag ds_reads + 4 MFMA clusters, NO internal barrier]  (every wave's
//    reads retire before its mm(1,0) via compiler lgkmcnt)
//   BAR-mid  -> all cur-buffer reads chip-wide retired
//   stage ALL 8 chunks of tile t+2 into cur (the buffer just finished)
//   vmcnt(8) -> outstanding = t+2's 8 just issued; t+1's 8 (issued at t-1) retired
//   BAR-end  -> t+1's LDS writes published; next tile reads oth safely.
// Prologue: t0(8)+t1(8), vmcnt(8) drains t0. Tail (no t+2): vmcnt(0).
// Per-acc-element MFMA order identical to R2 -> bitwise-identical C.
__device__ __forceinline__ void gemm256(const _Float16* __restrict__ A,
                                        const _Float16* __restrict__ Bt,
                                        _Float16* __restrict__ C, int ldc,
                                        int m0, int n0, _Float16* S) {
  _Float16* const As0 = S;
  _Float16* const As1 = S + 16384;
  _Float16* const Bs0 = S + 32768;
  _Float16* const Bs1 = S + 49152;
  const int tid = (int)threadIdx.x;
  const int lane = tid & 63, w = tid >> 6, l32 = lane & 31, half = lane >> 5;
  const int wm = (w & 1) * 128, wn = (w >> 1) * 64;

  f32x16 acc[4][2];
  #pragma unroll
  for (int s = 0; s < 4; ++s)
    #pragma unroll
    for (int t = 0; t < 2; ++t) acc[s][t] = 0;

  f16x8 af[2][4];   // current m-pair fragments (pair0 -> pair1 mid-tile)
  f16x8 bf[2][4];   // both n-frags, live across the whole K-tile

  auto stageA = [&](_Float16* dst, int ar, int kt) {
    const int r = tid >> 3, c = tid & 7;
    gload_lds16(A + (size_t)(m0 + ar + r) * 2048 + kt * 64 + ((c ^ (r & 7)) << 3),
                (char*)dst + ar * 128 + tid * 16);
  };
  auto stageB = [&](_Float16* dst, int br, int kt) {
    const int r = tid >> 3, c = tid & 7;
    gload_lds16(Bt + (size_t)(n0 + br + r) * 2048 + kt * 64 + ((c ^ (r & 7)) << 3),
                (char*)dst + br * 128 + tid * 16);
  };
  auto ldA = [&](const _Float16* as, int p) {
    #pragma unroll
    for (int s2 = 0; s2 < 2; ++s2)
      #pragma unroll
      for (int kk = 0; kk < 4; ++kk)
        af[s2][kk] = *(const f16x8*)(as + (wm + p * 64 + s2 * 32 + l32) * 64 +
                                     (((2 * kk + half) ^ (l32 & 7)) << 3));
  };
  auto ldB = [&](const _Float16* bs, int q) {
    #pragma unroll
    for (int kk = 0; kk < 4; ++kk)
      bf[q][kk] = *(const f16x8*)(bs + (wn + q * 32 + l32) * 64 +
                                  (((2 * kk + half) ^ (l32 & 7)) << 3));
  };
  auto mm8 = [&](int sp, int q) {
    __builtin_amdgcn_s_setprio(1);
    #pragma unroll
    for (int kk = 0; kk < 4; ++kk)
      #pragma unroll
      for (int s2 = 0; s2 < 2; ++s2)
        acc[sp * 2 + s2][q] = __builtin_amdgcn_mfma_f32_32x32x16_f16(
            bf[q][kk], af[s2][kk], acc[sp * 2 + s2][q], 0, 0, 0);
    __builtin_amdgcn_s_setprio(0);
  };

  // prologue: tile0 (8 chunks, oldest) + tile1 (8 chunks); vmcnt(8) drains t0
  stageA(As0, 0, 0); stageA(As0, 64, 0); stageA(As0, 128, 0); stageA(As0, 192, 0);
  stageB(Bs0, 0, 0); stageB(Bs0, 64, 0); stageB(Bs0, 128, 0); stageB(Bs0, 192, 0);
  stageA(As1, 0, 1); stageA(As1, 64, 1); stageA(As1, 128, 1); stageA(As1, 192, 1);
  stageB(Bs1, 0, 1); stageB(Bs1, 64, 1); stageB(Bs1, 128, 1); stageB(Bs1, 192, 1);
  WAITV8();
  BAR();

  auto tile = [&](int kt, _Float16* Ac, _Float16* Bc) {
    const bool g2 = (kt + 2) < 32;
    ldA(Ac, 0);                 // af <- pair0 (8 ds_reads)
    ldB(Bc, 0); ldB(Bc, 1);     // bf (8 ds_reads)
    mm8(0, 0);
    mm8(0, 1);
    ldA(Ac, 1);                 // af <- pair1 (8 ds_reads)
    mm8(1, 1);
    mm8(1, 0);                  // all cur reads retired per-wave here
    BAR();                      // mid: reads retired chip-wide
    if (g2) {
      stageA(Ac, 0, kt + 2); stageA(Ac, 64, kt + 2);
      stageA(Ac, 128, kt + 2); stageA(Ac, 192, kt + 2);
      stageB(Bc, 0, kt + 2); stageB(Bc, 64, kt + 2);
      stageB(Bc, 128, kt + 2); stageB(Bc, 192, kt + 2);
      WAITV8();                 // drains tile t+1's 8 chunks
    } else {
      WAITV0();
    }
    BAR();                      // end: t+1 published
  };

  #pragma unroll 1
  for (int kt = 0; kt < 32; kt += 2) {
    tile(kt, As0, Bs0);
    tile(kt + 1, As1, Bs1);
  }

  // epilogue: transposed-C frag -> row-contiguous f16x4 stores (C pre-offset)
  #pragma unroll
  for (int s = 0; s < 4; ++s) {
    const size_t row = (size_t)(wm + s * 32 + l32);
    #pragma unroll
    for (int t = 0; t < 2; ++t)
      #pragma unroll
      for (int g = 0; g < 4; ++g) {
        const int col = wn + t * 32 + g * 8 + 4 * half;
        f16x4 o = { (_Float16)acc[s][t][4 * g + 0], (_Float16)acc[s][t][4 * g + 1],
                    (_Float16)acc[s][t][4 * g + 2], (_Float16)acc[s][t][4 * g + 3] };
        *(f16x4*)(C + row * ldc + col) = o;
      }
  }
}

// ---- 128x256 pipelined GEMM, f16 out (proven R2 component, non-template).
// 8 waves (2M x 4N), wave tile 64x64, acc 2x2, LDS 96 KB, 2 barriers/K-tile.
__device__ __forceinline__ void gemm128h(const _Float16* __restrict__ A,
                                         const _Float16* __restrict__ Bt,
                                         _Float16* __restrict__ C, int ldc,
                                         int m0, int n0, _Float16* S) {
  _Float16* const As0 = S;             // 128 x 64
  _Float16* const As1 = S + 8192;
  _Float16* const Bs0 = S + 16384;     // 256 x 64
  _Float16* const Bs1 = S + 32768;
  const int tid = (int)threadIdx.x;
  const int lane = tid & 63, w = tid >> 6, l32 = lane & 31, half = lane >> 5;
  const int wm = (w & 1) * 64, wn = (w >> 1) * 64;

  f32x16 acc[2][2];
  #pragma unroll
  for (int s = 0; s < 2; ++s)
    #pragma unroll
    for (int t = 0; t < 2; ++t) acc[s][t] = 0;

  f16x8 af[2][4], bf[2][4];

  auto stA = [&](_Float16* dst, int ar, int kt) {
    const int r = tid >> 3, c = tid & 7;
    gload_lds16(A + (size_t)(m0 + ar + r) * 2048 + kt * 64 + ((c ^ (r & 7)) << 3),
                (char*)dst + ar * 128 + tid * 16);
  };
  auto stB = [&](_Float16* dst, int br, int kt) {
    const int r = tid >> 3, c = tid & 7;
    gload_lds16(Bt + (size_t)(n0 + br + r) * 2048 + kt * 64 + ((c ^ (r & 7)) << 3),
                (char*)dst + br * 128 + tid * 16);
  };
  auto ldAq = [&](const _Float16* as) {
    #pragma unroll
    for (int s2 = 0; s2 < 2; ++s2)
      #pragma unroll
      for (int kk = 0; kk < 4; ++kk)
        af[s2][kk] = *(const f16x8*)(as + (wm + s2 * 32 + l32) * 64 +
                                     (((2 * kk + half) ^ (l32 & 7)) << 3));
  };
  auto ldBq = [&](const _Float16* bs, int q) {
    #pragma unroll
    for (int kk = 0; kk < 4; ++kk)
      bf[q][kk] = *(const f16x8*)(bs + (wn + q * 32 + l32) * 64 +
                                  (((2 * kk + half) ^ (l32 & 7)) << 3));
  };
  auto mmq = [&](int q) {
    __builtin_amdgcn_s_setprio(1);
    #pragma unroll
    for (int kk = 0; kk < 4; ++kk)
      #pragma unroll
      for (int s2 = 0; s2 < 2; ++s2)
        acc[s2][q] = __builtin_amdgcn_mfma_f32_32x32x16_f16(
            bf[q][kk], af[s2][kk], acc[s2][q], 0, 0, 0);
    __builtin_amdgcn_s_setprio(0);
  };

  stA(As0, 0, 0); stA(As0, 64, 0);
  stB(Bs0, 0, 0); stB(Bs0, 64, 0); stB(Bs0, 128, 0); stB(Bs0, 192, 0);
  stA(As1, 0, 1); stA(As1, 64, 1);
  stB(Bs1, 0, 1); stB(Bs1, 64, 1); stB(Bs1, 128, 1); stB(Bs1, 192, 1);
  WAITV6();
  BAR();

  auto tile = [&](int kt, _Float16* Ac, _Float16* Bc) {
    const bool g2 = (kt + 2) < 32;
    ldAq(Ac); ldBq(Bc, 0); ldBq(Bc, 1);
    mmq(0);
    mmq(1);
    BAR();
    if (g2) {
      stA(Ac, 0, kt + 2); stA(Ac, 64, kt + 2);
      stB(Bc, 0, kt + 2); stB(Bc, 64, kt + 2); stB(Bc, 128, kt + 2); stB(Bc, 192, kt + 2);
      WAITV6();
    } else {
      WAITV0();
    }
    BAR();
  };

  #pragma unroll 1
  for (int kt = 0; kt < 32; kt += 2) {
    tile(kt, As0, Bs0);
    tile(kt + 1, As1, Bs1);
  }

  #pragma unroll
  for (int s = 0; s < 2; ++s) {
    const size_t row = (size_t)(wm + s * 32 + l32);
    #pragma unroll
    for (int t = 0; t < 2; ++t)
      #pragma unroll
      for (int g = 0; g < 4; ++g) {
        const int col = wn + t * 32 + g * 8 + 4 * half;
        f16x4 o = { (_Float16)acc[s][t][4 * g + 0], (_Float16)acc[s][t][4 * g + 1],
                    (_Float16)acc[s][t][4 * g + 2], (_Float16)acc[s][t][4 * g + 3] };
        *(f16x4*)(C + row * ldc + col) = o;
      }
  }
}

// ---- 128x256 pipelined GEMM, f32 out (separate copy: avoids template
// co-compilation codegen perturbation — rule #19, seen as +4.5us in R5) ----
__device__ __forceinline__ void gemm128f(const _Float16* __restrict__ A,
                                         const _Float16* __restrict__ Bt,
                                         float* __restrict__ C, int ldc,
                                         int m0, int n0, _Float16* S) {
  _Float16* const As0 = S;
  _Float16* const As1 = S + 8192;
  _Float16* const Bs0 = S + 16384;
  _Float16* const Bs1 = S + 32768;
  const int tid = (int)threadIdx.x;
  const int lane = tid & 63, w = tid >> 6, l32 = lane & 31, half = lane >> 5;
  const int wm = (w & 1) * 64, wn = (w >> 1) * 64;

  f32x16 acc[2][2];
  #pragma unroll
  for (int s = 0; s < 2; ++s)
    #pragma unroll
    for (int t = 0; t < 2; ++t) acc[s][t] = 0;

  f16x8 af[2][4], bf[2][4];

  auto stA = [&](_Float16* dst, int ar, int kt) {
    const int r = tid >> 3, c = tid & 7;
    gload_lds16(A + (size_t)(m0 + ar + r) * 2048 + kt * 64 + ((c ^ (r & 7)) << 3),
                (char*)dst + ar * 128 + tid * 16);
  };
  auto stB = [&](_Float16* dst, int br, int kt) {
    const int r = tid >> 3, c = tid & 7;
    gload_lds16(Bt + (size_t)(n0 + br + r) * 2048 + kt * 64 + ((c ^ (r & 7)) << 3),
                (char*)dst + br * 128 + tid * 16);
  };
  auto ldAq = [&](const _Float16* as) {
    #pragma unroll
    for (int s2 = 0; s2 < 2; ++s2)
      #pragma unroll
      for (int kk = 0; kk < 4; ++kk)
        af[s2][kk] = *(const f16x8*)(as + (wm + s2 * 32 + l32) * 64 +
                                     (((2 * kk + half) ^ (l32 & 7)) << 3));
  };
  auto ldBq = [&](const _Float16* bs, int q) {
    #pragma unroll
    for (int kk = 0; kk < 4; ++kk)
      bf[q][kk] = *(const f16x8*)(bs + (wn + q * 32 + l32) * 64 +
                                  (((2 * kk + half) ^ (l32 & 7)) << 3));
  };
  auto mmq = [&](int q) {
    __builtin_amdgcn_s_setprio(1);
    #pragma unroll
    for (int kk = 0; kk < 4; ++kk)
      #pragma unroll
      for (int s2 = 0; s2 < 2; ++s2)
        acc[s2][q] = __builtin_amdgcn_mfma_f32_32x32x16_f16(
            bf[q][kk], af[s2][kk], acc[s2][q], 0, 0, 0);
    __builtin_amdgcn_s_setprio(0);
  };

  stA(As0, 0, 0); stA(As0, 64, 0);
  stB(Bs0, 0, 0); stB(Bs0, 64, 0); stB(Bs0, 128, 0); stB(Bs0, 192, 0);
  stA(As1, 0, 1); stA(As1, 64, 1);
  stB(Bs1, 0, 1); stB(Bs1, 64, 1); stB(Bs1, 128, 1); stB(Bs1, 192, 1);
  WAITV6();
  BAR();

  auto tile = [&](int kt, _Float16* Ac, _Float16* Bc) {
    const bool g2 = (kt + 2) < 32;
    ldAq(Ac); ldBq(Bc, 0); ldBq(Bc, 1);
    mmq(0);
    mmq(1);
    BAR();
    if (g2) {
      stA(Ac, 0, kt + 2); stA(Ac, 64, kt + 2);
      stB(Bc, 0, kt + 2); stB(Bc, 64, kt + 2); stB(Bc, 128, kt + 2); stB(Bc, 192, kt + 2);
      WAITV6();
    } else {
      WAITV0();
    }
    BAR();
  };

  #pragma unroll 1
  for (int kt = 0; kt < 32; kt += 2) {
    tile(kt, As0, Bs0);
    tile(kt + 1, As1, Bs1);
  }

  #pragma unroll
  for (int s = 0; s < 2; ++s) {
    const size_t row = (size_t)(wm + s * 32 + l32);
    #pragma unroll
    for (int t = 0; t < 2; ++t)
      #pragma unroll
      for (int g = 0; g < 4; ++g) {
        const int col = wn + t * 32 + g * 8 + 4 * half;
        f32x4 o = { acc[s][t][4 * g + 0], acc[s][t][4 * g + 1],
                    acc[s][t][4 * g + 2], acc[s][t][4 * g + 3] };
        *(f32x4*)(C + row * ldc + col) = o;
      }
  }
}

// ---- fused QKV + V^T: 256 WGs x 512 thr, 1 WG/CU, balanced (1.5 tiles/CU) ----
__global__ __launch_bounds__(512, 2) void qkvv3(const _Float16* __restrict__ Hb,
                                                const _Float16* __restrict__ Wt,
                                                _Float16* __restrict__ Qb,
                                                _Float16* __restrict__ Kb,
                                                _Float16* __restrict__ Vtb) {
  __shared__ _Float16 S[65536];  // 128 KB
  const int id = blockIdx.x;
  {
    const int m0 = (id >> 4) * 256, n0 = (id & 15) * 256;
    _Float16* Cq = (n0 < 2048 ? Qb + n0 : Kb + (n0 - 2048)) + (size_t)m0 * 2048;
    gemm256(Hb, Wt, Cq, 2048, m0, n0, S);
  }
  WAITV0();   // drain epilogue stores: keep the next ledger's vmcnt clean
  BAR();
  {
    const int m0 = (id >> 4) * 128, n0 = (id & 15) * 256;
    gemm128h(Wt + (size_t)2 * 4194304, Hb, Vtb + (size_t)m0 * 4096 + n0,
             4096, m0, n0, S);
  }
}

// ---- Wo GEMM: pipelined 128x256 engine, 256 WGs (32m x 8n), 1/CU, f32 out ----
__global__ __launch_bounds__(512, 2) void gemm_wo(const _Float16* __restrict__ A,
                                                  const _Float16* __restrict__ Bt,
                                                  float* __restrict__ C) {
  __shared__ _Float16 S[49152];  // 96 KB
  const int t = blockIdx.x;
  const int m0 = (t >> 3) * 128, n0 = (t & 7) * 256;
  gemm128f(A, Bt, C + (size_t)m0 * 2048 + n0, 2048, m0, n0, S);
}

// ---- block-sparse attention: split K/V drain (R5/R6 version) ----
__global__ __launch_bounds__(256) void attn(const _Float16* __restrict__ Qg,
                                            const _Float16* __restrict__ Kg,
                                            const _Float16* __restrict__ Vtg,
                                            _Float16* __restrict__ Og) {
  const int t = blockIdx.x, h = blockIdx.y, b = blockIdx.z;
  __shared__ _Float16 Qs[128 * 128];  // 32 KB
  __shared__ _Float16 Ks[64 * 128];   // 16 KB
  __shared__ _Float16 Vs[128 * 64];   // 16 KB
  const int tid = threadIdx.x;
  const int lane = tid & 63, w = tid >> 6, l16 = lane & 15, quad = lane >> 4;
  const int qbw = 2 * t + (w >> 1);
  const char* QsB = (const char*)Qs;
  const char* KsB = (const char*)Ks;
  const char* VsB = (const char*)Vs;

  #pragma unroll
  for (int p = 0; p < 8; ++p) {
    int o = p * 256 + tid, r = o >> 4, c = o & 15;
    gload_lds16(Qg + (size_t)(b * 2048 + t * 128 + r) * 2048 + h * 128 + ((c ^ (r & 15)) * 8),
                (char*)Qs + o * 16);
  }
  __builtin_amdgcn_s_waitcnt(0);
  __syncthreads();
  f16x8 qf[2][4];
  #pragma unroll
  for (int qc = 0; qc < 2; ++qc)
    #pragma unroll
    for (int ks = 0; ks < 4; ++ks)
      qf[qc][ks] = *(const f16x8*)(QsB + (w * 32 + qc * 16 + l16) * 256 +
                                   (((ks * 4 + quad) ^ l16) * 16));

  const float scale = 0.08838834764831845f;  // 1/sqrt(128)
  float m_[2] = {-1e30f, -1e30f}, l_[2] = {0.f, 0.f};
  f32x4 oacc[8][2];
  #pragma unroll
  for (int dt = 0; dt < 8; ++dt)
    #pragma unroll
    for (int qc = 0; qc < 2; ++qc) oacc[dt][qc] = (f32x4){0.f, 0.f, 0.f, 0.f};

  for (int jj = 0; jj < 6; ++jj) {
    const int j = 2 * t - 2 + jj;
    const int jc = j < 0 ? 0 : (j > 31 ? 31 : j);
    __syncthreads();   // WAR: prev iter's Ks/Vs reads complete
    #pragma unroll
    for (int p = 0; p < 4; ++p) {
      int o = p * 256 + tid, r = o >> 4, c = o & 15;
      gload_lds16(Kg + (size_t)(b * 2048 + jc * 64 + r) * 2048 + h * 128 + ((c ^ (r & 15)) * 8),
                  (char*)Ks + o * 16);
    }
    #pragma unroll
    for (int p = 0; p < 4; ++p) {
      int o = p * 256 + tid, d = o >> 3, c = o & 7;
      gload_lds16(Vtg + (size_t)(h * 128 + d) * 4096 + b * 2048 + jc * 64 + ((c ^ (d & 7)) * 8),
                  (char*)Vs + o * 16);
    }
    WAITV4();   // K's 4 chunks retired; V's 4 still in flight
    BAR();

    const bool valid = (j >= 0) && (j <= 31) && (j >= qbw - 2) && (j <= qbw + 2);
    f32x4 sc[4][2];
    f16x4 pb[4][2];
    if (valid) {
      #pragma unroll
      for (int kt = 0; kt < 4; ++kt)
        #pragma unroll
        for (int qc = 0; qc < 2; ++qc) sc[kt][qc] = (f32x4){0.f, 0.f, 0.f, 0.f};
      #pragma unroll
      for (int kt = 0; kt < 4; ++kt)
        #pragma unroll
        for (int ks = 0; ks < 4; ++ks) {
          f16x8 kf = *(const f16x8*)(KsB + (kt * 16 + l16) * 256 + (((ks * 4 + quad) ^ l16) * 16));
          #pragma unroll
          for (int qc = 0; qc < 2; ++qc)
            sc[kt][qc] = __builtin_amdgcn_mfma_f32_16x16x32_f16(kf, qf[qc][ks], sc[kt][qc], 0, 0, 0);
        }
      #pragma unroll
      for (int qc = 0; qc < 2; ++qc) {
        float mj = -1e30f;
        #pragma unroll
        for (int kt = 0; kt < 4; ++kt)
          #pragma unroll
          for (int r = 0; r < 4; ++r) {
            float v = sc[kt][qc][r] * scale;
            sc[kt][qc][r] = v;
            mj = fmaxf(mj, v);
          }
        mj = fmaxf(mj, __shfl_xor(mj, 16));
        mj = fmaxf(mj, __shfl_xor(mj, 32));
        const float mn = fmaxf(m_[qc], mj);
        const float alpha = __expf(m_[qc] - mn);
        float s_ = 0.f;
        #pragma unroll
        for (int kt = 0; kt < 4; ++kt)
          #pragma unroll
          for (int r = 0; r < 4; ++r) {
            float p = __expf(sc[kt][qc][r] - mn);
            sc[kt][qc][r] = p;
            s_ += p;
          }
        s_ += __shfl_xor(s_, 16);
        s_ += __shfl_xor(s_, 32);
        l_[qc] = l_[qc] * alpha + s_;
        m_[qc] = mn;
        #pragma unroll
        for (int dt = 0; dt < 8; ++dt) oacc[dt][qc] *= alpha;
      }
      #pragma unroll
      for (int kt = 0; kt < 4; ++kt)
        #pragma unroll
        for (int qc = 0; qc < 2; ++qc)
          pb[kt][qc] = (f16x4){ (_Float16)sc[kt][qc][0], (_Float16)sc[kt][qc][1],
                                (_Float16)sc[kt][qc][2], (_Float16)sc[kt][qc][3] };
    }
    WAITV0();   // V landed
    BAR();
    if (valid) {
      #pragma unroll
      for (int kt = 0; kt < 4; ++kt) {
        #pragma unroll
        for (int dt = 0; dt < 8; ++dt) {
          f16x4 vv = *(const f16x4*)(VsB + (dt * 16 + l16) * 128 +
                                     (((2 * kt + (quad >> 1)) ^ (l16 & 7)) * 16) + (quad & 1) * 8);
          #pragma unroll
          for (int qc = 0; qc < 2; ++qc)
            oacc[dt][qc] = __builtin_amdgcn_mfma_f32_16x16x16f16(vv, pb[kt][qc], oacc[dt][qc], 0, 0, 0);
        }
      }
    }
  }

  #pragma unroll
  for (int qc = 0; qc < 2; ++qc) {
    const float pinv = 1.0f / l_[qc];
    const size_t orow = (size_t)(b * 2048 + t * 128 + w * 32 + qc * 16 + l16);
    #pragma unroll
    for (int dt = 0; dt < 8; ++dt) {
      f16x4 ov = { (_Float16)(oacc[dt][qc][0] * pinv), (_Float16)(oacc[dt][qc][1] * pinv),
                   (_Float16)(oacc[dt][qc][2] * pinv), (_Float16)(oacc[dt][qc][3] * pinv) };
      *(f16x4*)(Og + orow * 2048 + h * 128 + dt * 16 + quad * 4) = ov;
    }
  }
}

extern "C" void kernel_launch(void* const* d_in, const int* in_sizes, int n_in,
                              void* d_out, int out_size, void* d_ws, size_t ws_size,
                              hipStream_t stream) {
  const float* Hs = (const float*)d_in[0];
  const float* Wq = (const float*)d_in[1];
  const float* Wk = (const float*)d_in[2];
  const float* Wv = (const float*)d_in[3];
  const float* Wo = (const float*)d_in[4];
  _Float16* Hb  = (_Float16*)d_ws;          // H cast  [4096][2048]
  _Float16* Wt  = Hb  + 8388608;            // Wq/Wk/Wv/Wo^T  4 x [2048][2048]
  _Float16* Qb  = Wt  + 16777216;           // Q  [b*2048+s][h*128+d]
  _Float16* Kb  = Qb  + 8388608;            // K  [b*2048+s][h*128+d]
  _Float16* Vtb = Kb  + 8388608;            // V^T [h*128+d][b*2048+s]
  _Float16* Ob  = Vtb + 8388608;            // attn out [b*2048+s][h*128+d]
  float* out = (float*)d_out;

  prep<<<12288, 256, 0, stream>>>(Hs, Wq, Wk, Wv, Wo, Hb, Wt);
  qkvv3<<<256, 512, 0, stream>>>(Hb, Wt, Qb, Kb, Vtb);
  attn<<<dim3(16, 16, 2), 256, 0, stream>>>(Qb, Kb, Vtb, Ob);
  gemm_wo<<<256, 512, 0, stream>>>(Ob, Wt + (size_t)3 * 4194304, out);
}

// Round 8
// 334.690 us; speedup vs baseline: 1.0315x; 1.0272x over previous
//
#include <hip/hip_runtime.h>

typedef __attribute__((ext_vector_type(4))) float f32x4;
typedef __attribute__((ext_vector_type(16))) float f32x16;
typedef __attribute__((ext_vector_type(8))) _Float16 f16x8;
typedef __attribute__((ext_vector_type(4))) _Float16 f16x4;

__device__ __forceinline__ void gload_lds16(const void* g, void* l) {
  __builtin_amdgcn_global_load_lds((__attribute__((address_space(1))) void*)(g),
                                   (__attribute__((address_space(3))) void*)(l), 16, 0, 0);
}

#define BAR() asm volatile("s_barrier" ::: "memory")
#define LGKM0() asm volatile("s_waitcnt lgkmcnt(0)" ::: "memory")
#define WAITV6() asm volatile("s_waitcnt vmcnt(6)" ::: "memory")
#define WAITV4() asm volatile("s_waitcnt vmcnt(4)" ::: "memory")
#define WAITV0() asm volatile("s_waitcnt vmcnt(0)" ::: "memory")

// ---- fused prep: cast H fp32->fp16 (blocks 0..8191) + weight transpose-cast ----
__global__ __launch_bounds__(256) void prep(const float* __restrict__ Hs,
                                            const float* __restrict__ W0, const float* __restrict__ W1,
                                            const float* __restrict__ W2, const float* __restrict__ W3,
                                            _Float16* __restrict__ Hb, _Float16* __restrict__ Wt) {
  __shared__ _Float16 tile[64][65];
  const int bid = blockIdx.x, tid = threadIdx.x;
  if (bid < 8192) {
    int i = (bid * 256 + tid) * 4;
    float4 v = *(const float4*)(Hs + i);
    f16x4 o = { (_Float16)v.x, (_Float16)v.y, (_Float16)v.z, (_Float16)v.w };
    *(f16x4*)(Hb + i) = o;
    return;
  }
  const int t = bid - 8192;
  const int z = t >> 10, k0 = ((t >> 5) & 31) * 64, n0 = (t & 31) * 64;
  const float* W = z == 0 ? W0 : z == 1 ? W1 : z == 2 ? W2 : W3;
  _Float16* Wo_ = Wt + (size_t)z * (2048u * 2048u);
  #pragma unroll
  for (int p = 0; p < 4; ++p) {
    int o = p * 256 + tid, r = o >> 4, c = o & 15;
    float4 v = *(const float4*)(W + (size_t)(k0 + r) * 2048 + n0 + c * 4);
    tile[r][c * 4 + 0] = (_Float16)v.x;
    tile[r][c * 4 + 1] = (_Float16)v.y;
    tile[r][c * 4 + 2] = (_Float16)v.z;
    tile[r][c * 4 + 3] = (_Float16)v.w;
  }
  __syncthreads();
  #pragma unroll
  for (int p = 0; p < 2; ++p) {
    int o = p * 256 + tid, nl = o >> 3, c = o & 7;
    f16x8 u;
    #pragma unroll
    for (int i = 0; i < 8; ++i) u[i] = tile[c * 8 + i][nl];
    *(f16x8*)(Wo_ + (size_t)(n0 + nl) * 2048 + k0 + c * 8) = u;
  }
}

// ---- Q|K GEMM: m201-style 8-phase 256x256 template, 16x16x32 MFMA.
// 512 thr = 8 waves (2M x 4N); per-wave 128x64 = 8x4 frags of 16x16.
// BK=64, K=2048 -> 32 K-tiles, 2 per outer iter (buf0=even, buf1=odd).
// LDS 128 KB: A 256x64 x2 + B 256x64 x2. Chunk = 64 rows (1 G-load, 512x16B).
// Phase p = { ds-read subtile | stage 2 chunks | [vmcnt] } BAR LGKM0 16xMFMA BAR.
// Quadrant order per K-tile: (0,0),(0,1),(1,1),(1,0).
// Region-free ledger (tile t in buf0, read ph1-4): A chunks 0,2 free after ph1;
//   B all free after ph2; A chunks 1,3 free after ph3. (buf1 symmetric ph5-8.)
// Stage plan: ph1: t+1 A1,A3 | ph2: t+2 A0,A2 | ph3: t+2 B0,B1 | ph4: t+2 B2,B3
//   + vmcnt(6) [keeps ph2-4's 6 -> t+1 fully retired for ph5-8 reads]
//   | ph5: t+2 A1,A3 | ph6: t+3 A0,A2 | ph7: t+3 B0,B1 | ph8: t+3 B2,B3
//   + vmcnt(6) [keeps ph6-8's 6 -> t+2 fully retired for next ph1 reads].
// Tail (iter15): t+2/t+3 stages skipped; ph4/ph8 drop to vmcnt(0) (covers the
//   unconditionally-staged tile-31 A1,A3 read at ph7).
__global__ __launch_bounds__(512, 2) void qk8(const _Float16* __restrict__ A,
                                              const _Float16* __restrict__ Bt,
                                              _Float16* __restrict__ Qb,
                                              _Float16* __restrict__ Kb) {
  __shared__ _Float16 S[65536];  // 128 KB
  _Float16* const As0 = S;
  _Float16* const As1 = S + 16384;
  _Float16* const Bs0 = S + 32768;
  _Float16* const Bs1 = S + 49152;

  const int id = blockIdx.x;
  const int m0 = (id >> 4) * 256, n0 = (id & 15) * 256;
  _Float16* const C = (n0 < 2048 ? Qb + n0 : Kb + (n0 - 2048)) + (size_t)m0 * 2048;
  const int ldc = 2048;

  const int tid = (int)threadIdx.x;
  const int lane = tid & 63, w = tid >> 6, l16 = lane & 15, quad = lane >> 4;
  const int wm = (w & 1) * 128, wn = (w >> 1) * 64;

  f32x4 acc[8][4];
  #pragma unroll
  for (int fm = 0; fm < 8; ++fm)
    #pragma unroll
    for (int fn = 0; fn < 4; ++fn) acc[fm][fn] = (f32x4){0.f, 0.f, 0.f, 0.f};

  f16x8 af[4][2];      // A subtile for current qm: 4 m-frags x 2 ksteps
  f16x8 bf[2][2][2];   // B subtiles, both qn live: [qn][fn][ks]

  auto stA = [&](_Float16* dst, int ar, int kt) {
    const int r = tid >> 3, c = tid & 7;
    gload_lds16(A + (size_t)(m0 + ar + r) * 2048 + kt * 64 + ((c ^ (r & 7)) << 3),
                (char*)dst + ar * 128 + tid * 16);
  };
  auto stB = [&](_Float16* dst, int br, int kt) {
    const int r = tid >> 3, c = tid & 7;
    gload_lds16(Bt + (size_t)(n0 + br + r) * 2048 + kt * 64 + ((c ^ (r & 7)) << 3),
                (char*)dst + br * 128 + tid * 16);
  };
  // A-frag: lane reads row wm+qm*64+fm*16+l16, k-chunk ks*4+quad (16B), slot-XOR'd.
  auto ldA = [&](const _Float16* as, int qm) {
    #pragma unroll
    for (int fm = 0; fm < 4; ++fm)
      #pragma unroll
      for (int ks = 0; ks < 2; ++ks)
        af[fm][ks] = *(const f16x8*)(as + (wm + qm * 64 + fm * 16 + l16) * 64 +
                                     (((ks * 4 + quad) ^ (l16 & 7)) << 3));
  };
  auto ldB = [&](const _Float16* bs, int qn) {
    #pragma unroll
    for (int fn = 0; fn < 2; ++fn)
      #pragma unroll
      for (int ks = 0; ks < 2; ++ks)
        bf[qn][fn][ks] = *(const f16x8*)(bs + (wn + qn * 32 + fn * 16 + l16) * 64 +
                                         (((ks * 4 + quad) ^ (l16 & 7)) << 3));
  };
  // 16-MFMA cluster for quadrant (qm,qn). mfma(bf, af): lane&15 -> m, quad*4+reg -> n.
  auto mm16 = [&](int qm, int qn) {
    __builtin_amdgcn_s_setprio(1);
    #pragma unroll
    for (int ks = 0; ks < 2; ++ks)
      #pragma unroll
      for (int fm = 0; fm < 4; ++fm)
        #pragma unroll
        for (int fn = 0; fn < 2; ++fn)
          acc[qm * 4 + fm][qn * 2 + fn] = __builtin_amdgcn_mfma_f32_16x16x32_f16(
              bf[qn][fn][ks], af[fm][ks], acc[qm * 4 + fm][qn * 2 + fn], 0, 0, 0);
    __builtin_amdgcn_s_setprio(0);
  };

  // prologue: tile0 all 8 chunks (oldest) + tile1's A0,A2,B0..B3 (6);
  // vmcnt(6) retires tile0; tile1's A1,A3 staged at iter0 ph1 (steady pattern).
  stA(As0, 0, 0); stA(As0, 64, 0); stA(As0, 128, 0); stA(As0, 192, 0);
  stB(Bs0, 0, 0); stB(Bs0, 64, 0); stB(Bs0, 128, 0); stB(Bs0, 192, 0);
  stA(As1, 0, 1); stA(As1, 128, 1);
  stB(Bs1, 0, 1); stB(Bs1, 64, 1); stB(Bs1, 128, 1); stB(Bs1, 192, 1);
  WAITV6();
  BAR();

  #pragma unroll 1
  for (int I = 0; I < 16; ++I) {
    const int t1 = 2 * I + 1, t2 = 2 * I + 2, t3 = 2 * I + 3;
    const bool g2 = t2 < 32, g3 = t3 < 32;
    // ph1: (0,0) of tile 2I (buf0); stage t1 A1,A3 -> buf1 (read prev ph7, free)
    ldA(As0, 0); ldB(Bs0, 0);
    stA(As1, 64, t1); stA(As1, 192, t1);
    BAR(); LGKM0();
    mm16(0, 0);
    BAR();
    // ph2: (0,1); stage t2 A0,A2 -> buf0 (free after ph1)
    ldB(Bs0, 1);
    if (g2) { stA(As0, 0, t2); stA(As0, 128, t2); }
    BAR(); LGKM0();
    mm16(0, 1);
    BAR();
    // ph3: (1,1); stage t2 B0,B1 (B free after ph2)
    ldA(As0, 1);
    if (g2) { stB(Bs0, 0, t2); stB(Bs0, 64, t2); }
    BAR(); LGKM0();
    mm16(1, 1);
    BAR();
    // ph4: (1,0); stage t2 B2,B3; vmcnt(6) -> tile t1 fully landed for ph5-8
    if (g2) { stB(Bs0, 128, t2); stB(Bs0, 192, t2); WAITV6(); } else { WAITV0(); }
    BAR(); LGKM0();
    mm16(1, 0);
    BAR();
    // ph5: (0,0) of tile 2I+1 (buf1); stage t2 A1,A3 -> buf0 (free after ph3)
    ldA(As1, 0); ldB(Bs1, 0);
    if (g2) { stA(As0, 64, t2); stA(As0, 192, t2); }
    BAR(); LGKM0();
    mm16(0, 0);
    BAR();
    // ph6: (0,1); stage t3 A0,A2 -> buf1 (free after ph5)
    ldB(Bs1, 1);
    if (g3) { stA(As1, 0, t3); stA(As1, 128, t3); }
    BAR(); LGKM0();
    mm16(0, 1);
    BAR();
    // ph7: (1,1); stage t3 B0,B1 (buf1 B free after ph6)
    ldA(As1, 1);
    if (g3) { stB(Bs1, 0, t3); stB(Bs1, 64, t3); }
    BAR(); LGKM0();
    mm16(1, 1);
    BAR();
    // ph8: (1,0); stage t3 B2,B3; vmcnt(6) -> tile t2 fully landed for next ph1
    if (g3) { stB(Bs1, 128, t3); stB(Bs1, 192, t3); WAITV6(); } else { WAITV0(); }
    BAR(); LGKM0();
    mm16(1, 0);
    BAR();
  }

  // epilogue: lane holds C[m = wm+fm*16+l16][n = wn+fn*16+quad*4 .. +3]
  #pragma unroll
  for (int fm = 0; fm < 8; ++fm) {
    const size_t row = (size_t)(wm + fm * 16 + l16);
    #pragma unroll
    for (int fn = 0; fn < 4; ++fn) {
      const int col = wn + fn * 16 + quad * 4;
      f16x4 o = { (_Float16)acc[fm][fn][0], (_Float16)acc[fm][fn][1],
                  (_Float16)acc[fm][fn][2], (_Float16)acc[fm][fn][3] };
      *(f16x4*)(C + row * ldc + col) = o;
    }
  }
}

// ---- 128x256 pipelined GEMM, f16 out (proven R2/R6 component). ----
__device__ __forceinline__ void gemm128h(const _Float16* __restrict__ A,
                                         const _Float16* __restrict__ Bt,
                                         _Float16* __restrict__ C, int ldc,
                                         int m0, int n0, _Float16* S) {
  _Float16* const As0 = S;             // 128 x 64
  _Float16* const As1 = S + 8192;
  _Float16* const Bs0 = S + 16384;     // 256 x 64
  _Float16* const Bs1 = S + 32768;
  const int tid = (int)threadIdx.x;
  const int lane = tid & 63, w = tid >> 6, l32 = lane & 31, half = lane >> 5;
  const int wm = (w & 1) * 64, wn = (w >> 1) * 64;

  f32x16 acc[2][2];
  #pragma unroll
  for (int s = 0; s < 2; ++s)
    #pragma unroll
    for (int t = 0; t < 2; ++t) acc[s][t] = 0;

  f16x8 af[2][4], bf[2][4];

  auto stA = [&](_Float16* dst, int ar, int kt) {
    const int r = tid >> 3, c = tid & 7;
    gload_lds16(A + (size_t)(m0 + ar + r) * 2048 + kt * 64 + ((c ^ (r & 7)) << 3),
                (char*)dst + ar * 128 + tid * 16);
  };
  auto stB = [&](_Float16* dst, int br, int kt) {
    const int r = tid >> 3, c = tid & 7;
    gload_lds16(Bt + (size_t)(n0 + br + r) * 2048 + kt * 64 + ((c ^ (r & 7)) << 3),
                (char*)dst + br * 128 + tid * 16);
  };
  auto ldAq = [&](const _Float16* as) {
    #pragma unroll
    for (int s2 = 0; s2 < 2; ++s2)
      #pragma unroll
      for (int kk = 0; kk < 4; ++kk)
        af[s2][kk] = *(const f16x8*)(as + (wm + s2 * 32 + l32) * 64 +
                                     (((2 * kk + half) ^ (l32 & 7)) << 3));
  };
  auto ldBq = [&](const _Float16* bs, int q) {
    #pragma unroll
    for (int kk = 0; kk < 4; ++kk)
      bf[q][kk] = *(const f16x8*)(bs + (wn + q * 32 + l32) * 64 +
                                  (((2 * kk + half) ^ (l32 & 7)) << 3));
  };
  auto mmq = [&](int q) {
    __builtin_amdgcn_s_setprio(1);
    #pragma unroll
    for (int kk = 0; kk < 4; ++kk)
      #pragma unroll
      for (int s2 = 0; s2 < 2; ++s2)
        acc[s2][q] = __builtin_amdgcn_mfma_f32_32x32x16_f16(
            bf[q][kk], af[s2][kk], acc[s2][q], 0, 0, 0);
    __builtin_amdgcn_s_setprio(0);
  };

  stA(As0, 0, 0); stA(As0, 64, 0);
  stB(Bs0, 0, 0); stB(Bs0, 64, 0); stB(Bs0, 128, 0); stB(Bs0, 192, 0);
  stA(As1, 0, 1); stA(As1, 64, 1);
  stB(Bs1, 0, 1); stB(Bs1, 64, 1); stB(Bs1, 128, 1); stB(Bs1, 192, 1);
  WAITV6();
  BAR();

  auto tile = [&](int kt, _Float16* Ac, _Float16* Bc) {
    const bool g2 = (kt + 2) < 32;
    ldAq(Ac); ldBq(Bc, 0); ldBq(Bc, 1);
    mmq(0);
    mmq(1);
    BAR();
    if (g2) {
      stA(Ac, 0, kt + 2); stA(Ac, 64, kt + 2);
      stB(Bc, 0, kt + 2); stB(Bc, 64, kt + 2); stB(Bc, 128, kt + 2); stB(Bc, 192, kt + 2);
      WAITV6();
    } else {
      WAITV0();
    }
    BAR();
  };

  #pragma unroll 1
  for (int kt = 0; kt < 32; kt += 2) {
    tile(kt, As0, Bs0);
    tile(kt + 1, As1, Bs1);
  }

  #pragma unroll
  for (int s = 0; s < 2; ++s) {
    const size_t row = (size_t)(wm + s * 32 + l32);
    #pragma unroll
    for (int t = 0; t < 2; ++t)
      #pragma unroll
      for (int g = 0; g < 4; ++g) {
        const int col = wn + t * 32 + g * 8 + 4 * half;
        f16x4 o = { (_Float16)acc[s][t][4 * g + 0], (_Float16)acc[s][t][4 * g + 1],
                    (_Float16)acc[s][t][4 * g + 2], (_Float16)acc[s][t][4 * g + 3] };
        *(f16x4*)(C + row * ldc + col) = o;
      }
  }
}

// ---- 128x256 pipelined GEMM, f32 out (separate copy, rule #19) ----
__device__ __forceinline__ void gemm128f(const _Float16* __restrict__ A,
                                         const _Float16* __restrict__ Bt,
                                         float* __restrict__ C, int ldc,
                                         int m0, int n0, _Float16* S) {
  _Float16* const As0 = S;
  _Float16* const As1 = S + 8192;
  _Float16* const Bs0 = S + 16384;
  _Float16* const Bs1 = S + 32768;
  const int tid = (int)threadIdx.x;
  const int lane = tid & 63, w = tid >> 6, l32 = lane & 31, half = lane >> 5;
  const int wm = (w & 1) * 64, wn = (w >> 1) * 64;

  f32x16 acc[2][2];
  #pragma unroll
  for (int s = 0; s < 2; ++s)
    #pragma unroll
    for (int t = 0; t < 2; ++t) acc[s][t] = 0;

  f16x8 af[2][4], bf[2][4];

  auto stA = [&](_Float16* dst, int ar, int kt) {
    const int r = tid >> 3, c = tid & 7;
    gload_lds16(A + (size_t)(m0 + ar + r) * 2048 + kt * 64 + ((c ^ (r & 7)) << 3),
                (char*)dst + ar * 128 + tid * 16);
  };
  auto stB = [&](_Float16* dst, int br, int kt) {
    const int r = tid >> 3, c = tid & 7;
    gload_lds16(Bt + (size_t)(n0 + br + r) * 2048 + kt * 64 + ((c ^ (r & 7)) << 3),
                (char*)dst + br * 128 + tid * 16);
  };
  auto ldAq = [&](const _Float16* as) {
    #pragma unroll
    for (int s2 = 0; s2 < 2; ++s2)
      #pragma unroll
      for (int kk = 0; kk < 4; ++kk)
        af[s2][kk] = *(const f16x8*)(as + (wm + s2 * 32 + l32) * 64 +
                                     (((2 * kk + half) ^ (l32 & 7)) << 3));
  };
  auto ldBq = [&](const _Float16* bs, int q) {
    #pragma unroll
    for (int kk = 0; kk < 4; ++kk)
      bf[q][kk] = *(const f16x8*)(bs + (wn + q * 32 + l32) * 64 +
                                  (((2 * kk + half) ^ (l32 & 7)) << 3));
  };
  auto mmq = [&](int q) {
    __builtin_amdgcn_s_setprio(1);
    #pragma unroll
    for (int kk = 0; kk < 4; ++kk)
      #pragma unroll
      for (int s2 = 0; s2 < 2; ++s2)
        acc[s2][q] = __builtin_amdgcn_mfma_f32_32x32x16_f16(
            bf[q][kk], af[s2][kk], acc[s2][q], 0, 0, 0);
    __builtin_amdgcn_s_setprio(0);
  };

  stA(As0, 0, 0); stA(As0, 64, 0);
  stB(Bs0, 0, 0); stB(Bs0, 64, 0); stB(Bs0, 128, 0); stB(Bs0, 192, 0);
  stA(As1, 0, 1); stA(As1, 64, 1);
  stB(Bs1, 0, 1); stB(Bs1, 64, 1); stB(Bs1, 128, 1); stB(Bs1, 192, 1);
  WAITV6();
  BAR();

  auto tile = [&](int kt, _Float16* Ac, _Float16* Bc) {
    const bool g2 = (kt + 2) < 32;
    ldAq(Ac); ldBq(Bc, 0); ldBq(Bc, 1);
    mmq(0);
    mmq(1);
    BAR();
    if (g2) {
      stA(Ac, 0, kt + 2); stA(Ac, 64, kt + 2);
      stB(Bc, 0, kt + 2); stB(Bc, 64, kt + 2); stB(Bc, 128, kt + 2); stB(Bc, 192, kt + 2);
      WAITV6();
    } else {
      WAITV0();
    }
    BAR();
  };

  #pragma unroll 1
  for (int kt = 0; kt < 32; kt += 2) {
    tile(kt, As0, Bs0);
    tile(kt + 1, As1, Bs1);
  }

  #pragma unroll
  for (int s = 0; s < 2; ++s) {
    const size_t row = (size_t)(wm + s * 32 + l32);
    #pragma unroll
    for (int t = 0; t < 2; ++t)
      #pragma unroll
      for (int g = 0; g < 4; ++g) {
        const int col = wn + t * 32 + g * 8 + 4 * half;
        f32x4 o = { acc[s][t][4 * g + 0], acc[s][t][4 * g + 1],
                    acc[s][t][4 * g + 2], acc[s][t][4 * g + 3] };
        *(f32x4*)(C + row * ldc + col) = o;
      }
  }
}

// ---- V^T GEMM: 256 WGs x 512 thr, 1 WG/CU. C[2048][4096] = WvT . Hb^T ----
__global__ __launch_bounds__(512, 2) void vt(const _Float16* __restrict__ Hb,
                                             const _Float16* __restrict__ WvT,
                                             _Float16* __restrict__ Vtb) {
  __shared__ _Float16 S[49152];  // 96 KB
  const int id = blockIdx.x;
  const int m0 = (id >> 4) * 128, n0 = (id & 15) * 256;
  gemm128h(WvT, Hb, Vtb + (size_t)m0 * 4096 + n0, 4096, m0, n0, S);
}

// ---- Wo GEMM: pipelined 128x256 engine, 256 WGs (32m x 8n), 1/CU, f32 out ----
__global__ __launch_bounds__(512, 2) void gemm_wo(const _Float16* __restrict__ A,
                                                  const _Float16* __restrict__ Bt,
                                                  float* __restrict__ C) {
  __shared__ _Float16 S[49152];  // 96 KB
  const int t = blockIdx.x;
  const int m0 = (t >> 3) * 128, n0 = (t & 7) * 256;
  gemm128f(A, Bt, C + (size_t)m0 * 2048 + n0, 2048, m0, n0, S);
}

// ---- block-sparse attention: split K/V drain (R5/R6/R7 version) ----
__global__ __launch_bounds__(256) void attn(const _Float16* __restrict__ Qg,
                                            const _Float16* __restrict__ Kg,
                                            const _Float16* __restrict__ Vtg,
                                            _Float16* __restrict__ Og) {
  const int t = blockIdx.x, h = blockIdx.y, b = blockIdx.z;
  __shared__ _Float16 Qs[128 * 128];  // 32 KB
  __shared__ _Float16 Ks[64 * 128];   // 16 KB
  __shared__ _Float16 Vs[128 * 64];   // 16 KB
  const int tid = threadIdx.x;
  const int lane = tid & 63, w = tid >> 6, l16 = lane & 15, quad = lane >> 4;
  const int qbw = 2 * t + (w >> 1);
  const char* QsB = (const char*)Qs;
  const char* KsB = (const char*)Ks;
  const char* VsB = (const char*)Vs;

  #pragma unroll
  for (int p = 0; p < 8; ++p) {
    int o = p * 256 + tid, r = o >> 4, c = o & 15;
    gload_lds16(Qg + (size_t)(b * 2048 + t * 128 + r) * 2048 + h * 128 + ((c ^ (r & 15)) * 8),
                (char*)Qs + o * 16);
  }
  __builtin_amdgcn_s_waitcnt(0);
  __syncthreads();
  f16x8 qf[2][4];
  #pragma unroll
  for (int qc = 0; qc < 2; ++qc)
    #pragma unroll
    for (int ks = 0; ks < 4; ++ks)
      qf[qc][ks] = *(const f16x8*)(QsB + (w * 32 + qc * 16 + l16) * 256 +
                                   (((ks * 4 + quad) ^ l16) * 16));

  const float scale = 0.08838834764831845f;  // 1/sqrt(128)
  float m_[2] = {-1e30f, -1e30f}, l_[2] = {0.f, 0.f};
  f32x4 oacc[8][2];
  #pragma unroll
  for (int dt = 0; dt < 8; ++dt)
    #pragma unroll
    for (int qc = 0; qc < 2; ++qc) oacc[dt][qc] = (f32x4){0.f, 0.f, 0.f, 0.f};

  for (int jj = 0; jj < 6; ++jj) {
    const int j = 2 * t - 2 + jj;
    const int jc = j < 0 ? 0 : (j > 31 ? 31 : j);
    __syncthreads();   // WAR: prev iter's Ks/Vs reads complete
    #pragma unroll
    for (int p = 0; p < 4; ++p) {
      int o = p * 256 + tid, r = o >> 4, c = o & 15;
      gload_lds16(Kg + (size_t)(b * 2048 + jc * 64 + r) * 2048 + h * 128 + ((c ^ (r & 15)) * 8),
                  (char*)Ks + o * 16);
    }
    #pragma unroll
    for (int p = 0; p < 4; ++p) {
      int o = p * 256 + tid, d = o >> 3, c = o & 7;
      gload_lds16(Vtg + (size_t)(h * 128 + d) * 4096 + b * 2048 + jc * 64 + ((c ^ (d & 7)) * 8),
                  (char*)Vs + o * 16);
    }
    WAITV4();   // K's 4 chunks retired; V's 4 still in flight
    BAR();

    const bool valid = (j >= 0) && (j <= 31) && (j >= qbw - 2) && (j <= qbw + 2);
    f32x4 sc[4][2];
    f16x4 pb[4][2];
    if (valid) {
      #pragma unroll
      for (int kt = 0; kt < 4; ++kt)
        #pragma unroll
        for (int qc = 0; qc < 2; ++qc) sc[kt][qc] = (f32x4){0.f, 0.f, 0.f, 0.f};
      #pragma unroll
      for (int kt = 0; kt < 4; ++kt)
        #pragma unroll
        for (int ks = 0; ks < 4; ++ks) {
          f16x8 kf = *(const f16x8*)(KsB + (kt * 16 + l16) * 256 + (((ks * 4 + quad) ^ l16) * 16));
          #pragma unroll
          for (int qc = 0; qc < 2; ++qc)
            sc[kt][qc] = __builtin_amdgcn_mfma_f32_16x16x32_f16(kf, qf[qc][ks], sc[kt][qc], 0, 0, 0);
        }
      #pragma unroll
      for (int qc = 0; qc < 2; ++qc) {
        float mj = -1e30f;
        #pragma unroll
        for (int kt = 0; kt < 4; ++kt)
          #pragma unroll
          for (int r = 0; r < 4; ++r) {
            float v = sc[kt][qc][r] * scale;
            sc[kt][qc][r] = v;
            mj = fmaxf(mj, v);
          }
        mj = fmaxf(mj, __shfl_xor(mj, 16));
        mj = fmaxf(mj, __shfl_xor(mj, 32));
        const float mn = fmaxf(m_[qc], mj);
        const float alpha = __expf(m_[qc] - mn);
        float s_ = 0.f;
        #pragma unroll
        for (int kt = 0; kt < 4; ++kt)
          #pragma unroll
          for (int r = 0; r < 4; ++r) {
            float p = __expf(sc[kt][qc][r] - mn);
            sc[kt][qc][r] = p;
            s_ += p;
          }
        s_ += __shfl_xor(s_, 16);
        s_ += __shfl_xor(s_, 32);
        l_[qc] = l_[qc] * alpha + s_;
        m_[qc] = mn;
        #pragma unroll
        for (int dt = 0; dt < 8; ++dt) oacc[dt][qc] *= alpha;
      }
      #pragma unroll
      for (int kt = 0; kt < 4; ++kt)
        #pragma unroll
        for (int qc = 0; qc < 2; ++qc)
          pb[kt][qc] = (f16x4){ (_Float16)sc[kt][qc][0], (_Float16)sc[kt][qc][1],
                                (_Float16)sc[kt][qc][2], (_Float16)sc[kt][qc][3] };
    }
    WAITV0();   // V landed
    BAR();
    if (valid) {
      #pragma unroll
      for (int kt = 0; kt < 4; ++kt) {
        #pragma unroll
        for (int dt = 0; dt < 8; ++dt) {
          f16x4 vv = *(const f16x4*)(VsB + (dt * 16 + l16) * 128 +
                                     (((2 * kt + (quad >> 1)) ^ (l16 & 7)) * 16) + (quad & 1) * 8);
          #pragma unroll
          for (int qc = 0; qc < 2; ++qc)
            oacc[dt][qc] = __builtin_amdgcn_mfma_f32_16x16x16f16(vv, pb[kt][qc], oacc[dt][qc], 0, 0, 0);
        }
      }
    }
  }

  #pragma unroll
  for (int qc = 0; qc < 2; ++qc) {
    const float pinv = 1.0f / l_[qc];
    const size_t orow = (size_t)(b * 2048 + t * 128 + w * 32 + qc * 16 + l16);
    #pragma unroll
    for (int dt = 0; dt < 8; ++dt) {
      f16x4 ov = { (_Float16)(oacc[dt][qc][0] * pinv), (_Float16)(oacc[dt][qc][1] * pinv),
                   (_Float16)(oacc[dt][qc][2] * pinv), (_Float16)(oacc[dt][qc][3] * pinv) };
      *(f16x4*)(Og + orow * 2048 + h * 128 + dt * 16 + quad * 4) = ov;
    }
  }
}

extern "C" void kernel_launch(void* const* d_in, const int* in_sizes, int n_in,
                              void* d_out, int out_size, void* d_ws, size_t ws_size,
                              hipStream_t stream) {
  const float* Hs = (const float*)d_in[0];
  const float* Wq = (const float*)d_in[1];
  const float* Wk = (const float*)d_in[2];
  const float* Wv = (const float*)d_in[3];
  const float* Wo = (const float*)d_in[4];
  _Float16* Hb  = (_Float16*)d_ws;          // H cast  [4096][2048]
  _Float16* Wt  = Hb  + 8388608;            // Wq/Wk/Wv/Wo^T  4 x [2048][2048]
  _Float16* Qb  = Wt  + 16777216;           // Q  [b*2048+s][h*128+d]
  _Float16* Kb  = Qb  + 8388608;            // K  [b*2048+s][h*128+d]
  _Float16* Vtb = Kb  + 8388608;            // V^T [h*128+d][b*2048+s]
  _Float16* Ob  = Vtb + 8388608;            // attn out [b*2048+s][h*128+d]
  float* out = (float*)d_out;

  prep<<<12288, 256, 0, stream>>>(Hs, Wq, Wk, Wv, Wo, Hb, Wt);
  qk8<<<256, 512, 0, stream>>>(Hb, Wt, Qb, Kb);
  vt<<<256, 512, 0, stream>>>(Hb, Wt + (size_t)2 * 4194304, Vtb);
  attn<<<dim3(16, 16, 2), 256, 0, stream>>>(Qb, Kb, Vtb, Ob);
  gemm_wo<<<256, 512, 0, stream>>>(Ob, Wt + (size_t)3 * 4194304, out);
}